// Round 4
// baseline (114.770 us; speedup 1.0000x reference)
//
#include <hip/hip_runtime.h>
#include <math.h>

// PhaseShift: out = unwrap(atan2(xi,xr) - atan2(xi[ch0],xr[ch0]), axis=F)
// Shapes: [N=16, CH=4, F=513, T=512] fp32.
//
// Block = (n, t-tile of 32), 1024 threads = 32 t-lanes x 32 F-segments of 17,
// ALL channels fused: a0 = atan2(ch0) computed once, pc_c = atan2(ch_c) - a0
// is BIT-IDENTICAL to the per-channel version (safety: absmax margin is
// 0.5/3.58 and any change to the dd bit-sequence re-rolls the pi-boundary
// flip lottery; ±2pi flip = fail). Register arrays q[3][17] hold pc+local
// correction prefix (no spill cliff: 16-wave block pins residency at
// 4 waves/SIMD, VGPR budget 512/wave). Everything is unconditional via
// clamp-to-row-512: clamped iterations recompute identical values and
// redundantly store identical bits (benign). LDS scan of 32 per-segment
// correction sums -> cross-segment offset. fmodf replaced by bounded exact
// reduction (<=2 steps, differs from fmodf by <=1 ULP, only affects ddmod).

#define NN    16
#define CHN   4
#define FF    513
#define TT    512
#define PLANE (FF * TT)      // 262656
#define NSEG  32
#define SEG   17             // 32*17 = 544 >= 513

__device__ __forceinline__ float phase_corr(float dd) {
    // np.unwrap step: ddmod = pymod(dd+pi, 2pi) - pi; edge rule; gate |dd|<pi.
    // dd in (-4pi, 4pi) -> x = dd+pi in (-3pi, 5pi): <=2 exact +-2pi steps.
    const float PIF  = 3.14159265358979323846f;   // 0x40490FDB
    const float TPIF = 6.28318530717958647692f;   // 0x40C90FDB = 2*PIF exactly
    float x = dd + PIF;
    x = (x >= TPIF) ? x - TPIF : x;
    x = (x >= TPIF) ? x - TPIF : x;
    x = (x < 0.0f)  ? x + TPIF : x;
    x = (x < 0.0f)  ? x + TPIF : x;
    float ddmod = x - PIF;
    if (ddmod == -PIF && dd > 0.0f) ddmod = PIF;
    return (fabsf(dd) < PIF) ? 0.0f : (ddmod - dd);
}

__global__ __launch_bounds__(1024) void phase_unwrap_kernel(
    const float* __restrict__ xr, const float* __restrict__ xi,
    float* __restrict__ out)
{
    const int tid   = threadIdx.x;
    const int tl    = tid & 31;      // t within tile
    const int seg   = tid >> 5;      // 0..31 F-segment
    const int bid   = blockIdx.x;
    const int ttile = bid & 15;      // 16 tiles of 32 t
    const int n     = bid >> 4;
    const int t     = ttile * 32 + tl;

    // 32-bit element offsets: max ~16.8M << 2^32
    const unsigned base = (unsigned)(n * CHN * PLANE) + (unsigned)t;
    const int f0 = seg * SEG;

    __shared__ float segsum[3][NSEG][32];

    // Boundary phases at f0-1 (clamped; seg 0 skips corr at k=0 anyway).
    float pprev0 = 0.0f, pprev1 = 0.0f, pprev2 = 0.0f;
    if (seg > 0) {
        int fb = f0 - 1; fb = (fb > FF - 1) ? (FF - 1) : fb;
        const unsigned off = base + (unsigned)fb * TT;
        const float a0 = atan2f(xi[off], xr[off]);
        pprev0 = atan2f(xi[off + 1u * PLANE], xr[off + 1u * PLANE]) - a0;
        pprev1 = atan2f(xi[off + 2u * PLANE], xr[off + 2u * PLANE]) - a0;
        pprev2 = atan2f(xi[off + 3u * PLANE], xr[off + 3u * PLANE]) - a0;
    }

    float acc0 = 0.0f, acc1 = 0.0f, acc2 = 0.0f;
    float q0[SEG], q1[SEG], q2[SEG];

    // Pass 1: shared a0, three independent correction chains, q in registers.
    #pragma unroll
    for (int k = 0; k < SEG; ++k) {
        int f = f0 + k; f = (f > FF - 1) ? (FF - 1) : f;   // clamp: dd=0, corr=0
        const unsigned off = base + (unsigned)f * TT;
        const float a0  = atan2f(xi[off], xr[off]);
        const float pc0 = atan2f(xi[off + 1u * PLANE], xr[off + 1u * PLANE]) - a0;
        const float pc1 = atan2f(xi[off + 2u * PLANE], xr[off + 2u * PLANE]) - a0;
        const float pc2 = atan2f(xi[off + 3u * PLANE], xr[off + 3u * PLANE]) - a0;
        if (seg > 0 || k > 0) {        // k>0 folds at compile time
            acc0 += phase_corr(pc0 - pprev0);
            acc1 += phase_corr(pc1 - pprev1);
            acc2 += phase_corr(pc2 - pprev2);
        }
        q0[k] = pc0 + acc0;
        q1[k] = pc1 + acc1;
        q2[k] = pc2 + acc2;
        pprev0 = pc0; pprev1 = pc1; pprev2 = pc2;
    }

    segsum[0][seg][tl] = acc0;
    segsum[1][seg][tl] = acc1;
    segsum[2][seg][tl] = acc2;
    __syncthreads();

    // Exclusive prefix over segments (31 predicated adds per channel).
    float run0 = 0.0f, run1 = 0.0f, run2 = 0.0f;
    #pragma unroll
    for (int v = 0; v < NSEG - 1; ++v) {
        if (v < seg) {
            run0 += segsum[0][v][tl];
            run1 += segsum[1][v][tl];
            run2 += segsum[2][v][tl];
        }
    }

    // Pass 2: stores only (ch0 = exact zero). Clamped k rewrite identical bits.
    #pragma unroll
    for (int k = 0; k < SEG; ++k) {
        int f = f0 + k; f = (f > FF - 1) ? (FF - 1) : f;
        const unsigned off = base + (unsigned)f * TT;
        out[off]              = 0.0f;
        out[off + 1u * PLANE] = q0[k] + run0;
        out[off + 2u * PLANE] = q1[k] + run1;
        out[off + 3u * PLANE] = q2[k] + run2;
    }
}

extern "C" void kernel_launch(void* const* d_in, const int* in_sizes, int n_in,
                              void* d_out, int out_size, void* d_ws, size_t ws_size,
                              hipStream_t stream) {
    const float* xr = (const float*)d_in[0];
    const float* xi = (const float*)d_in[1];
    float* out = (float*)d_out;

    dim3 grid(NN * (TT / 32));   // 256 blocks = 1 block/CU
    dim3 block(1024);            // 32 segments x 32 t
    phase_unwrap_kernel<<<grid, block, 0, stream>>>(xr, xi, out);
}

// Round 5
// 54.306 us; speedup vs baseline: 2.1134x; 2.1134x over previous
//
#include <hip/hip_runtime.h>
#include <math.h>

// PhaseShift: out = unwrap(atan2(xi,xr) - atan2(xi[ch0],xr[ch0]), axis=F)
// Shapes: [N=16, CH=4, F=513, T=512] fp32.
//
// R3 streaming skeleton (NO per-thread arrays -- R1/R2/R4 all spilled them
// to scratch) + R4's validated VALU cuts:
//  - channel fusion: a0 = atan2(ch0) computed ONCE per (t,f); pc_c =
//    atan2(ch_c) - a0 is bit-identical to the per-channel version (absmax
//    margin 0.5/3.58; any dd bit change re-rolls the pi-boundary lottery).
//  - bounded exact mod (<=2 +-2pi steps) instead of fmodf.
// Block = (n, t-tile of 32): 1024 threads = 32 t-lanes x 32 F-segments of
// 17. Pass 1 streams pc+acc to out (ch0 = exact 0). LDS scan of per-segment
// correction sums; pass 2 RMWs out += run (L2-resident). cnt-guarded: no
// clamping (clamped RMW would double-add).

#define NN    16
#define CHN   4
#define FF    513
#define TT    512
#define PLANE (FF * TT)      // 262656
#define NSEG  32
#define SEG   17             // segs 0..29 full, seg 30 -> 3 rows, seg 31 idle

__device__ __forceinline__ float phase_corr(float dd) {
    // np.unwrap step: ddmod = pymod(dd+pi, 2pi) - pi; edge rule; gate |dd|<pi.
    // dd in (-4pi, 4pi) -> x = dd+pi in (-3pi, 5pi): <=2 exact +-2pi steps.
    const float PIF  = 3.14159265358979323846f;   // 0x40490FDB
    const float TPIF = 6.28318530717958647692f;   // 0x40C90FDB = 2*PIF exactly
    float x = dd + PIF;
    x = (x >= TPIF) ? x - TPIF : x;
    x = (x >= TPIF) ? x - TPIF : x;
    x = (x < 0.0f)  ? x + TPIF : x;
    x = (x < 0.0f)  ? x + TPIF : x;
    float ddmod = x - PIF;
    if (ddmod == -PIF && dd > 0.0f) ddmod = PIF;
    return (fabsf(dd) < PIF) ? 0.0f : (ddmod - dd);
}

__global__ __launch_bounds__(1024) void phase_unwrap_kernel(
    const float* __restrict__ xr, const float* __restrict__ xi,
    float* __restrict__ out)
{
    const int tid   = threadIdx.x;
    const int tl    = tid & 31;      // t within tile
    const int seg   = tid >> 5;      // 0..31 F-segment
    const int bid   = blockIdx.x;
    const int ttile = bid & 15;      // 16 tiles of 32 t
    const int n     = bid >> 4;
    const int t     = ttile * 32 + tl;

    const unsigned base = (unsigned)(n * CHN * PLANE) + (unsigned)t;
    const int f0  = seg * SEG;
    const int cnt = min(SEG, FF - f0);   // 17 / 3 / <=0

    __shared__ float segsum[3][NSEG][32];

    // Boundary phases at f0-1 (valid whenever cnt>0: f0-1 <= 509).
    float pprev0 = 0.0f, pprev1 = 0.0f, pprev2 = 0.0f;
    if (seg > 0 && cnt > 0) {
        const unsigned off = base + (unsigned)(f0 - 1) * TT;
        const float a0 = atan2f(xi[off], xr[off]);
        pprev0 = atan2f(xi[off + 1u * PLANE], xr[off + 1u * PLANE]) - a0;
        pprev1 = atan2f(xi[off + 2u * PLANE], xr[off + 2u * PLANE]) - a0;
        pprev2 = atan2f(xi[off + 3u * PLANE], xr[off + 3u * PLANE]) - a0;
    }

    // Pass 1: shared a0, three correction chains, stream stores.
    float acc0 = 0.0f, acc1 = 0.0f, acc2 = 0.0f;
    #pragma unroll 4
    for (int k = 0; k < cnt; ++k) {
        const unsigned off = base + (unsigned)(f0 + k) * TT;
        const float a0  = atan2f(xi[off], xr[off]);
        const float pc0 = atan2f(xi[off + 1u * PLANE], xr[off + 1u * PLANE]) - a0;
        const float pc1 = atan2f(xi[off + 2u * PLANE], xr[off + 2u * PLANE]) - a0;
        const float pc2 = atan2f(xi[off + 3u * PLANE], xr[off + 3u * PLANE]) - a0;
        if (seg > 0 || k > 0) {
            acc0 += phase_corr(pc0 - pprev0);
            acc1 += phase_corr(pc1 - pprev1);
            acc2 += phase_corr(pc2 - pprev2);
        }
        out[off]              = 0.0f;          // ch0: exact zero
        out[off + 1u * PLANE] = pc0 + acc0;
        out[off + 2u * PLANE] = pc1 + acc1;
        out[off + 3u * PLANE] = pc2 + acc2;
        pprev0 = pc0; pprev1 = pc1; pprev2 = pc2;
    }

    segsum[0][seg][tl] = acc0;
    segsum[1][seg][tl] = acc1;
    segsum[2][seg][tl] = acc2;
    __syncthreads();

    if (seg > 0 && cnt > 0) {
        // Exclusive prefix over segments (predicated adds; broadcast reads).
        float run0 = 0.0f, run1 = 0.0f, run2 = 0.0f;
        #pragma unroll
        for (int v = 0; v < NSEG - 1; ++v) {
            if (v < seg) {
                run0 += segsum[0][v][tl];
                run1 += segsum[1][v][tl];
                run2 += segsum[2][v][tl];
            }
        }
        // Pass 2: RMW our freshly-written (L2-resident) rows. No clamping!
        #pragma unroll 4
        for (int k = 0; k < cnt; ++k) {
            const unsigned off = base + (unsigned)(f0 + k) * TT;
            out[off + 1u * PLANE] += run0;
            out[off + 2u * PLANE] += run1;
            out[off + 3u * PLANE] += run2;
        }
    }
}

extern "C" void kernel_launch(void* const* d_in, const int* in_sizes, int n_in,
                              void* d_out, int out_size, void* d_ws, size_t ws_size,
                              hipStream_t stream) {
    const float* xr = (const float*)d_in[0];
    const float* xi = (const float*)d_in[1];
    float* out = (float*)d_out;

    dim3 grid(NN * (TT / 32));   // 256 blocks = 1 block/CU
    dim3 block(1024);            // 32 segments x 32 t-lanes
    phase_unwrap_kernel<<<grid, block, 0, stream>>>(xr, xi, out);
}

// Round 6
// 53.494 us; speedup vs baseline: 2.1455x; 1.0152x over previous
//
#include <hip/hip_runtime.h>
#include <math.h>

// PhaseShift: out = unwrap(atan2(xi,xr) - atan2(xi[ch0],xr[ch0]), axis=F)
// Shapes: [N=16, CH=4, F=513, T=512] fp32.
//
// R5 streaming skeleton (NO per-thread arrays -- R1/R2/R4 all spilled) +
// latency-hiding round:
//  - unroll 8 (VGPR headroom is huge at 1 block/CU: 4 waves/SIMD -> 512 cap)
//  - balanced segments: SEGB=16, last seg takes 17 rows
//  - nontemporal stores for FINAL data (ch0 zeros, pass-2 results) so the
//    134 MB of inputs stay L3-resident across replays; pass-1 ch1-3 stores
//    stay cached (pass-2 RMW re-reads them through L2).
// dd bit-sequence unchanged (channel fusion a0 shared; bounded exact mod) --
// the pi-boundary flip lottery is not re-rolled. Only final-sum association
// at segment boundaries moves (ULP noise vs 3.58 threshold).

#define NN    16
#define CHN   4
#define FF    513
#define TT    512
#define PLANE (FF * TT)      // 262656
#define NSEG  32
#define SEGB  16             // segs 0..30: 16 rows; seg 31: 17 rows

__device__ __forceinline__ float phase_corr(float dd) {
    // np.unwrap step: ddmod = pymod(dd+pi, 2pi) - pi; edge rule; gate |dd|<pi.
    // dd in (-4pi, 4pi) -> x = dd+pi in (-3pi, 5pi): <=2 exact +-2pi steps.
    const float PIF  = 3.14159265358979323846f;   // 0x40490FDB
    const float TPIF = 6.28318530717958647692f;   // 0x40C90FDB = 2*PIF exactly
    float x = dd + PIF;
    x = (x >= TPIF) ? x - TPIF : x;
    x = (x >= TPIF) ? x - TPIF : x;
    x = (x < 0.0f)  ? x + TPIF : x;
    x = (x < 0.0f)  ? x + TPIF : x;
    float ddmod = x - PIF;
    if (ddmod == -PIF && dd > 0.0f) ddmod = PIF;
    return (fabsf(dd) < PIF) ? 0.0f : (ddmod - dd);
}

__global__ __launch_bounds__(1024) void phase_unwrap_kernel(
    const float* __restrict__ xr, const float* __restrict__ xi,
    float* __restrict__ out)
{
    const int tid   = threadIdx.x;
    const int tl    = tid & 31;      // t within tile
    const int seg   = tid >> 5;      // 0..31 F-segment
    const int bid   = blockIdx.x;
    const int ttile = bid & 15;      // 16 tiles of 32 t
    const int n     = bid >> 4;
    const int t     = ttile * 32 + tl;

    const unsigned base = (unsigned)(n * CHN * PLANE) + (unsigned)t;
    const int f0  = seg * SEGB;
    const int cnt = (seg == NSEG - 1) ? (FF - f0) : SEGB;   // 16, last 17

    __shared__ float segsum[3][NSEG][32];

    // Boundary phases at f0-1 (segs 1..31).
    float pprev0 = 0.0f, pprev1 = 0.0f, pprev2 = 0.0f;
    if (seg > 0) {
        const unsigned off = base + (unsigned)(f0 - 1) * TT;
        const float a0 = atan2f(xi[off], xr[off]);
        pprev0 = atan2f(xi[off + 1u * PLANE], xr[off + 1u * PLANE]) - a0;
        pprev1 = atan2f(xi[off + 2u * PLANE], xr[off + 2u * PLANE]) - a0;
        pprev2 = atan2f(xi[off + 3u * PLANE], xr[off + 3u * PLANE]) - a0;
    }

    // Pass 1: shared a0, three correction chains, stream stores.
    float acc0 = 0.0f, acc1 = 0.0f, acc2 = 0.0f;
    unsigned off = base + (unsigned)f0 * TT;
    #pragma unroll 8
    for (int k = 0; k < cnt; ++k, off += TT) {
        const float a0  = atan2f(xi[off], xr[off]);
        const float pc0 = atan2f(xi[off + 1u * PLANE], xr[off + 1u * PLANE]) - a0;
        const float pc1 = atan2f(xi[off + 2u * PLANE], xr[off + 2u * PLANE]) - a0;
        const float pc2 = atan2f(xi[off + 3u * PLANE], xr[off + 3u * PLANE]) - a0;
        if (seg > 0 || k > 0) {            // k>0 folds in unrolled bodies
            acc0 += phase_corr(pc0 - pprev0);
            acc1 += phase_corr(pc1 - pprev1);
            acc2 += phase_corr(pc2 - pprev2);
        }
        __builtin_nontemporal_store(0.0f, &out[off]);   // ch0: final, never re-read
        out[off + 1u * PLANE] = pc0 + acc0;             // cached: RMW re-reads
        out[off + 2u * PLANE] = pc1 + acc1;
        out[off + 3u * PLANE] = pc2 + acc2;
        pprev0 = pc0; pprev1 = pc1; pprev2 = pc2;
    }

    segsum[0][seg][tl] = acc0;
    segsum[1][seg][tl] = acc1;
    segsum[2][seg][tl] = acc2;
    __syncthreads();

    if (seg > 0) {
        // Exclusive prefix over segments, ascending v (same order as R5).
        float run0 = 0.0f, run1 = 0.0f, run2 = 0.0f;
        for (int v = 0; v < seg; ++v) {
            run0 += segsum[0][v][tl];
            run1 += segsum[1][v][tl];
            run2 += segsum[2][v][tl];
        }
        // Pass 2: RMW our own freshly-written rows (L2-hot read), nt final store.
        unsigned o2 = base + (unsigned)f0 * TT;
        #pragma unroll 4
        for (int k = 0; k < cnt; ++k, o2 += TT) {
            const float v0 = out[o2 + 1u * PLANE] + run0;
            const float v1 = out[o2 + 2u * PLANE] + run1;
            const float v2 = out[o2 + 3u * PLANE] + run2;
            __builtin_nontemporal_store(v0, &out[o2 + 1u * PLANE]);
            __builtin_nontemporal_store(v1, &out[o2 + 2u * PLANE]);
            __builtin_nontemporal_store(v2, &out[o2 + 3u * PLANE]);
        }
    }
}

extern "C" void kernel_launch(void* const* d_in, const int* in_sizes, int n_in,
                              void* d_out, int out_size, void* d_ws, size_t ws_size,
                              hipStream_t stream) {
    const float* xr = (const float*)d_in[0];
    const float* xi = (const float*)d_in[1];
    float* out = (float*)d_out;

    dim3 grid(NN * (TT / 32));   // 256 blocks = 1 block/CU
    dim3 block(1024);            // 32 segments x 32 t-lanes
    phase_unwrap_kernel<<<grid, block, 0, stream>>>(xr, xi, out);
}